// Round 7
// baseline (71.294 us; speedup 1.0000x reference)
//
#include <hip/hip_runtime.h>
#include <math.h>

#define NBATCH 128
#define NP 256
#define NC 64
#define KNN 16
#define EPSV 1e-3f

typedef __bf16 bf16_t;
typedef bf16_t bf16x8 __attribute__((ext_vector_type(8)));
typedef float f32x4 __attribute__((ext_vector_type(4)));

static __device__ __forceinline__ f32x4 mfma16(bf16x8 a, bf16x8 b, f32x4 c) {
    return __builtin_amdgcn_mfma_f32_16x16x32_bf16(a, b, c, 0, 0, 0);
}
static __device__ __forceinline__ unsigned short f2bfu(float f) {
    union { bf16_t b; unsigned short u; } cv; cv.b = (bf16_t)f; return cv.u;
}
static __device__ __forceinline__ bf16x8 pack8(float4 a, float4 b) {
    bf16x8 r;
    r[0] = (bf16_t)a.x; r[1] = (bf16_t)a.y; r[2] = (bf16_t)a.z; r[3] = (bf16_t)a.w;
    r[4] = (bf16_t)b.x; r[5] = (bf16_t)b.y; r[6] = (bf16_t)b.z; r[7] = (bf16_t)b.w;
    return r;
}
// wave-private LDS ordering fence (rule #18: asm waitcnt needs sched_barrier)
#define LDS_FENCE() do { asm volatile("s_waitcnt lgkmcnt(0)" ::: "memory"); \
                         __builtin_amdgcn_sched_barrier(0); } while (0)

// 16-level predicated sorted insertion on packed u32 keys
// key = (float_bits(d) & 0xFFFFFF00) | idx  -> total order, low idx wins ties
#define INSERTK(k_)                                                   \
    do {                                                              \
        _Pragma("unroll")                                             \
        for (int ii = KNN - 1; ii >= 1; --ii) {                       \
            const bool wr = (k_) < bk[ii];                            \
            const bool sh = (k_) < bk[ii - 1];                        \
            const unsigned nv = sh ? bk[ii - 1] : (k_);               \
            if (wr) bk[ii] = nv;                                      \
        }                                                             \
        if ((k_) < bk[0]) bk[0] = (k_);                               \
    } while (0)

// ---------------------------------------------------------------------------
// kNN v4: 4-way candidate split. Block = 256 thr serves 64 queries; thread
// t: query qbase+(t&63), quarter (t>>6) scans 64 candidates. Tree merge via
// LDS (sorted lists, early-break inserts). Grid = 4*NBATCH = 512 blocks.
// ---------------------------------------------------------------------------
__global__ __launch_bounds__(256) void knn_kernel(const float* __restrict__ points,
                                                  int* __restrict__ idx_out) {
    const int bb = blockIdx.x >> 2;
    const int qbase = (blockIdx.x & 3) * 64;
    const int t = threadIdx.x;
    const int qt = t & 63;
    const int quarter = t >> 6;
    const int p = qbase + qt;            // my query (within batch)

    __shared__ __align__(16) float4 sp[NP];
    __shared__ unsigned mA[64][17];      // quarter1 list, then 2U3 merged list
    __shared__ unsigned mB[64][17];      // quarter3 list

    const float* pb = points + (size_t)bb * NP * 3;
    sp[t] = make_float4(pb[t * 3 + 0], pb[t * 3 + 1], pb[t * 3 + 2], 0.f);
    __syncthreads();

    const float4 qp = sp[p];
    unsigned bk[KNN];
#pragma unroll
    for (int i = 0; i < KNN; ++i) bk[i] = 0xFFFFFFFFu;

    const int cbase = quarter * 64;      // wave-uniform
#pragma unroll 4
    for (int c = 0; c < 64; ++c) {
        const int cand = cbase + c;
        const float4 P = sp[cand];       // wave-uniform addr -> LDS broadcast
        const float dx = qp.x - P.x, dy = qp.y - P.y, dz = qp.z - P.z;
        const float d = fmaf(dx, dx, fmaf(dy, dy, dz * dz));
        unsigned key = (__float_as_uint(d) & 0xFFFFFF00u) | (unsigned)cand;
        key = (cand == p) ? 0xFFFFFFFFu : key;   // self-exclusion, branchless
        INSERTK(key);
    }

    // stage 1: quarters 1,3 publish; 0 merges 1, 2 merges 3
    if (quarter == 1) { for (int i = 0; i < KNN; ++i) mA[qt][i] = bk[i]; }
    if (quarter == 3) { for (int i = 0; i < KNN; ++i) mB[qt][i] = bk[i]; }
    __syncthreads();
    if (quarter == 0 || quarter == 2) {
        const unsigned* src = (quarter == 0) ? mA[qt] : mB[qt];
        for (int j = 0; j < KNN; ++j) {
            const unsigned key = src[j];
            if (key >= bk[KNN - 1]) break;
            INSERTK(key);
        }
    }
    __syncthreads();
    // stage 2: quarter 2 publishes merged (2U3); quarter 0 merges it
    if (quarter == 2) { for (int i = 0; i < KNN; ++i) mA[qt][i] = bk[i]; }
    __syncthreads();
    if (quarter == 0) {
        for (int j = 0; j < KNN; ++j) {
            const unsigned key = mA[qt][j];
            if (key >= bk[KNN - 1]) break;
            INSERTK(key);
        }
        int* op = idx_out + ((size_t)bb * NP + p) * KNN;
#pragma unroll
        for (int i = 0; i < KNN; ++i) op[i] = (int)(bk[i] & 0xFFu);
    }
}

// ---------------------------------------------------------------------------
// Prep (unchanged): lay out weights in MFMA B-fragment order + fold BN params.
// B-frag (16x16x32): lane l holds B[ks*32 + (l>>4)*8 + j][t*16 + (l&15)].
// ---------------------------------------------------------------------------
__global__ __launch_bounds__(256) void prep_kernel(
    const float* __restrict__ w0, const float* __restrict__ w1,
    const float* __restrict__ w2, const float* __restrict__ sc_w,
    const float* __restrict__ gammas, const float* __restrict__ betas,
    const float* __restrict__ means, const float* __restrict__ variances,
    const float* __restrict__ sc_gamma, const float* __restrict__ sc_beta,
    const float* __restrict__ sc_mean, const float* __restrict__ sc_var,
    unsigned short* __restrict__ wsf, float* __restrict__ bnp)
{
    const int tid = blockIdx.x * 256 + threadIdx.x;
    if (tid < 20480) {
        const float* src;
        int base;
        if (tid < 8192)       { src = w0;   base = 0; }
        else if (tid < 12288) { src = w1;   base = 8192; }
        else if (tid < 16384) { src = w2;   base = 12288; }
        else                  { src = sc_w; base = 16384; }
        const int e2 = tid - base;
        const int f = e2 >> 9;
        const int r = e2 & 511;
        const int lane = r >> 3, j = r & 7;
        const int ks = f >> 2, t = f & 3;
        const int row = ks * 32 + (lane >> 4) * 8 + j;
        const int col = t * 16 + (lane & 15);
        wsf[tid] = f2bfu(src[row * 64 + col]);
    } else {
        const int e = tid - 20480;
        if (e < 192) {
            float s = gammas[e] * rsqrtf(variances[e] + EPSV);
            bnp[e] = s;
            bnp[192 + e] = betas[e] - means[e] * s;
        } else if (e < 256) {
            const int d = e - 192;
            float s = sc_gamma[d] * rsqrtf(sc_var[d] + EPSV);
            bnp[384 + d] = s;
            bnp[448 + d] = sc_beta[d] - sc_mean[d] * s;
        }
    }
}

// ---------------------------------------------------------------------------
// Edge MLP v3: one wave per block, 8 points, processed as 4 iterations of
// TWO interleaved independent chains (points 2k, 2k+1, separate LDS slabs,
// shared fences). Doubles schedulable work between fences; fences drop from
// 3/point to 1.5/point. XCD-swizzled blockIdx (features L2-resident).
// ---------------------------------------------------------------------------
__global__ __launch_bounds__(64, 2) void edge_kernel(
    const float* __restrict__ features, const int* __restrict__ knn_idx,
    const unsigned short* __restrict__ wsf, const float* __restrict__ bnp,
    float* __restrict__ out)
{
    __shared__ __align__(16) unsigned short sA0[16 * 72];  // chain0 L1 out
    __shared__ __align__(16) unsigned short sA1[16 * 72];  // chain1 L1 out
    __shared__ __align__(16) unsigned short sB0[16 * 72];  // chain0 L2 out
    __shared__ __align__(16) unsigned short sB1[16 * 72];  // chain1 L2 out
    __shared__ float ftsbuf[8][64];   // [point q][channel]

    const int l = threadIdx.x;
    const int i = l & 15;
    const int h = l >> 4;
    // bijective XCD swizzle: 4096 blocks = 8 XCDs x 512 contiguous work items
    const int wg = (blockIdx.x & 7) * 512 + (blockIdx.x >> 3);
    const int p0 = wg * 8;
    const int b = p0 >> 8;

    const bf16x8* __restrict__ W0 = (const bf16x8*)(wsf);
    const bf16x8* __restrict__ W1 = (const bf16x8*)(wsf + 8192);
    const bf16x8* __restrict__ W2 = (const bf16x8*)(wsf + 12288);

    // layer weights resident in registers for the whole wave lifetime
    bf16x8 w0r[4][4], w1r[2][4], w2r[2][4];
#pragma unroll
    for (int ks = 0; ks < 4; ++ks)
#pragma unroll
        for (int t = 0; t < 4; ++t) w0r[ks][t] = W0[(ks * 4 + t) * 64 + l];
#pragma unroll
    for (int ks = 0; ks < 2; ++ks)
#pragma unroll
        for (int t = 0; t < 4; ++t) {
            w1r[ks][t] = W1[(ks * 4 + t) * 64 + l];
            w2r[ks][t] = W2[(ks * 4 + t) * 64 + l];
        }

    float scl[3][4], shf[3][4];
#pragma unroll
    for (int L = 0; L < 3; ++L)
#pragma unroll
        for (int t = 0; t < 4; ++t) {
            scl[L][t] = bnp[L * 64 + t * 16 + i];
            shf[L][t] = bnp[192 + L * 64 + t * 16 + i];
        }

    // preload this wave's 8 neighbor indices (lane's k = i)
    int nks[8];
#pragma unroll
    for (int q = 0; q < 8; ++q) nks[q] = knn_idx[(size_t)(p0 + q) * KNN + i];

    for (int k = 0; k < 4; ++k) {
        const int q0 = 2 * k, q1 = 2 * k + 1;
        // ---- gather + pack, both chains (independent -> schedulable) ----
        bf16x8 fA0[4], fA1[4];
        {
            const float* cp = features + (size_t)(p0 + q0) * NC;
            const float* sp = features + (size_t)(b * NP + nks[q0]) * NC;
            float4 c0 = *(const float4*)(cp + h * 8);
            float4 c1 = *(const float4*)(cp + h * 8 + 4);
            float4 c2 = *(const float4*)(cp + 32 + h * 8);
            float4 c3 = *(const float4*)(cp + 32 + h * 8 + 4);
            float4 n0 = *(const float4*)(sp + h * 8);
            float4 n1 = *(const float4*)(sp + h * 8 + 4);
            float4 n2 = *(const float4*)(sp + 32 + h * 8);
            float4 n3 = *(const float4*)(sp + 32 + h * 8 + 4);
            n0.x -= c0.x; n0.y -= c0.y; n0.z -= c0.z; n0.w -= c0.w;
            n1.x -= c1.x; n1.y -= c1.y; n1.z -= c1.z; n1.w -= c1.w;
            n2.x -= c2.x; n2.y -= c2.y; n2.z -= c2.z; n2.w -= c2.w;
            n3.x -= c3.x; n3.y -= c3.y; n3.z -= c3.z; n3.w -= c3.w;
            fA0[0] = pack8(c0, c1); fA0[1] = pack8(c2, c3);
            fA0[2] = pack8(n0, n1); fA0[3] = pack8(n2, n3);
        }
        {
            const float* cp = features + (size_t)(p0 + q1) * NC;
            const float* sp = features + (size_t)(b * NP + nks[q1]) * NC;
            float4 c0 = *(const float4*)(cp + h * 8);
            float4 c1 = *(const float4*)(cp + h * 8 + 4);
            float4 c2 = *(const float4*)(cp + 32 + h * 8);
            float4 c3 = *(const float4*)(cp + 32 + h * 8 + 4);
            float4 n0 = *(const float4*)(sp + h * 8);
            float4 n1 = *(const float4*)(sp + h * 8 + 4);
            float4 n2 = *(const float4*)(sp + 32 + h * 8);
            float4 n3 = *(const float4*)(sp + 32 + h * 8 + 4);
            n0.x -= c0.x; n0.y -= c0.y; n0.z -= c0.z; n0.w -= c0.w;
            n1.x -= c1.x; n1.y -= c1.y; n1.z -= c1.z; n1.w -= c1.w;
            n2.x -= c2.x; n2.y -= c2.y; n2.z -= c2.z; n2.w -= c2.w;
            n3.x -= c3.x; n3.y -= c3.y; n3.z -= c3.z; n3.w -= c3.w;
            fA1[0] = pack8(c0, c1); fA1[1] = pack8(c2, c3);
            fA1[2] = pack8(n0, n1); fA1[3] = pack8(n2, n3);
        }

        // ---- layer 1, both chains ----
#pragma unroll
        for (int t = 0; t < 4; ++t) {
            f32x4 a0 = {0.f, 0.f, 0.f, 0.f}, a1 = {0.f, 0.f, 0.f, 0.f};
#pragma unroll
            for (int ks = 0; ks < 4; ++ks) {
                a0 = mfma16(fA0[ks], w0r[ks][t], a0);
                a1 = mfma16(fA1[ks], w0r[ks][t], a1);
            }
#pragma unroll
            for (int r = 0; r < 4; ++r) {
                float y0 = fmaxf(fmaf(a0[r], scl[0][t], shf[0][t]), 0.f);
                float y1 = fmaxf(fmaf(a1[r], scl[0][t], shf[0][t]), 0.f);
                sA0[(h * 4 + r) * 72 + t * 16 + i] = f2bfu(y0);
                sA1[(h * 4 + r) * 72 + t * 16 + i] = f2bfu(y1);
            }
        }
        LDS_FENCE();

        // ---- layer 2, both chains ----
        {
            bf16x8 x00 = *(const bf16x8*)(sA0 + i * 72 + h * 8);
            bf16x8 x01 = *(const bf16x8*)(sA0 + i * 72 + h * 8 + 32);
            bf16x8 x10 = *(const bf16x8*)(sA1 + i * 72 + h * 8);
            bf16x8 x11 = *(const bf16x8*)(sA1 + i * 72 + h * 8 + 32);
#pragma unroll
            for (int t = 0; t < 4; ++t) {
                f32x4 a0 = {0.f, 0.f, 0.f, 0.f}, a1 = {0.f, 0.f, 0.f, 0.f};
                a0 = mfma16(x00, w1r[0][t], a0);
                a1 = mfma16(x10, w1r[0][t], a1);
                a0 = mfma16(x01, w1r[1][t], a0);
                a1 = mfma16(x11, w1r[1][t], a1);
#pragma unroll
                for (int r = 0; r < 4; ++r) {
                    float y0 = fmaxf(fmaf(a0[r], scl[1][t], shf[1][t]), 0.f);
                    float y1 = fmaxf(fmaf(a1[r], scl[1][t], shf[1][t]), 0.f);
                    sB0[(h * 4 + r) * 72 + t * 16 + i] = f2bfu(y0);
                    sB1[(h * 4 + r) * 72 + t * 16 + i] = f2bfu(y1);
                }
            }
        }
        LDS_FENCE();

        // ---- layer 3 + mean over k, both chains ----
        {
            bf16x8 x00 = *(const bf16x8*)(sB0 + i * 72 + h * 8);
            bf16x8 x01 = *(const bf16x8*)(sB0 + i * 72 + h * 8 + 32);
            bf16x8 x10 = *(const bf16x8*)(sB1 + i * 72 + h * 8);
            bf16x8 x11 = *(const bf16x8*)(sB1 + i * 72 + h * 8 + 32);
#pragma unroll
            for (int t = 0; t < 4; ++t) {
                f32x4 a0 = {0.f, 0.f, 0.f, 0.f}, a1 = {0.f, 0.f, 0.f, 0.f};
                a0 = mfma16(x00, w2r[0][t], a0);
                a1 = mfma16(x10, w2r[0][t], a1);
                a0 = mfma16(x01, w2r[1][t], a0);
                a1 = mfma16(x11, w2r[1][t], a1);
                float s0 = 0.f, s1 = 0.f;
#pragma unroll
                for (int r = 0; r < 4; ++r) {
                    s0 += fmaxf(fmaf(a0[r], scl[2][t], shf[2][t]), 0.f);
                    s1 += fmaxf(fmaf(a1[r], scl[2][t], shf[2][t]), 0.f);
                }
                s0 += __shfl_xor(s0, 16, 64);
                s0 += __shfl_xor(s0, 32, 64);
                s1 += __shfl_xor(s1, 16, 64);
                s1 += __shfl_xor(s1, 32, 64);
                if (h == 0) {
                    ftsbuf[q0][t * 16 + i] = s0 * (1.f / 16.f);
                    ftsbuf[q1][t * 16 + i] = s1 * (1.f / 16.f);
                }
            }
        }
        LDS_FENCE();  // slab WAR for next iter + ftsbuf visibility
    }

    // ---- shortcut GEMM + epilogue: rows 0..7 = this wave's 8 points ----
    {
        const bf16x8* __restrict__ WS = (const bf16x8*)(wsf + 16384);
        float sscl[4], sshf[4];
#pragma unroll
        for (int t = 0; t < 4; ++t) {
            sscl[t] = bnp[384 + t * 16 + i];
            sshf[t] = bnp[448 + t * 16 + i];
        }
        const float* fp = features + (size_t)(p0 + (i & 7)) * NC;  // rows 8..15 dup
        float4 c0 = *(const float4*)(fp + h * 8);
        float4 c1 = *(const float4*)(fp + h * 8 + 4);
        float4 c2 = *(const float4*)(fp + 32 + h * 8);
        float4 c3 = *(const float4*)(fp + 32 + h * 8 + 4);
        bf16x8 a0 = pack8(c0, c1), a1 = pack8(c2, c3);
#pragma unroll
        for (int t = 0; t < 4; ++t) {
            f32x4 acc = {0.f, 0.f, 0.f, 0.f};
            acc = mfma16(a0, WS[t * 64 + l], acc);
            acc = mfma16(a1, WS[(4 + t) * 64 + l], acc);
            if (h < 2) {   // C rows 0..7 = real points; 8..15 are duplicates
#pragma unroll
                for (int r = 0; r < 4; ++r) {
                    const int q = h * 4 + r;
                    out[(size_t)(p0 + q) * NC + t * 16 + i] =
                        fmaxf(fmaf(acc[r], sscl[t], sshf[t]) + ftsbuf[q][t * 16 + i], 0.f);
                }
            }
        }
    }
}

extern "C" void kernel_launch(void* const* d_in, const int* in_sizes, int n_in,
                              void* d_out, int out_size, void* d_ws, size_t ws_size,
                              hipStream_t stream) {
    const float* points    = (const float*)d_in[0];
    const float* features  = (const float*)d_in[1];
    const float* w0        = (const float*)d_in[2];
    const float* w1        = (const float*)d_in[3];
    const float* w2        = (const float*)d_in[4];
    const float* gammas    = (const float*)d_in[5];
    const float* betas     = (const float*)d_in[6];
    const float* means     = (const float*)d_in[7];
    const float* variances = (const float*)d_in[8];
    const float* sc_w      = (const float*)d_in[9];
    const float* sc_gamma  = (const float*)d_in[10];
    const float* sc_beta   = (const float*)d_in[11];
    const float* sc_mean   = (const float*)d_in[12];
    const float* sc_var    = (const float*)d_in[13];
    float* out = (float*)d_out;

    int* knn_buf = (int*)d_ws;                                        // 2 MB
    unsigned short* wsf = (unsigned short*)((char*)d_ws + (1 << 21)); // 40 KB
    float* bnp = (float*)((char*)d_ws + (1 << 21) + 40960);           // 1.8 KB

    prep_kernel<<<81, 256, 0, stream>>>(w0, w1, w2, sc_w, gammas, betas, means,
                                        variances, sc_gamma, sc_beta, sc_mean,
                                        sc_var, wsf, bnp);
    knn_kernel<<<NBATCH * 4, 256, 0, stream>>>(points, knn_buf);
    edge_kernel<<<NBATCH * NP / 8, 64, 0, stream>>>(features, knn_buf, wsf, bnp, out);
}

// Round 8
// 67.788 us; speedup vs baseline: 1.0517x; 1.0517x over previous
//
#include <hip/hip_runtime.h>
#include <math.h>

#define NBATCH 128
#define NP 256
#define NC 64
#define KNN 16
#define EPSV 1e-3f

typedef __bf16 bf16_t;
typedef bf16_t bf16x8 __attribute__((ext_vector_type(8)));
typedef float f32x4 __attribute__((ext_vector_type(4)));

static __device__ __forceinline__ f32x4 mfma16(bf16x8 a, bf16x8 b, f32x4 c) {
    return __builtin_amdgcn_mfma_f32_16x16x32_bf16(a, b, c, 0, 0, 0);
}
static __device__ __forceinline__ unsigned short f2bfu(float f) {
    union { bf16_t b; unsigned short u; } cv; cv.b = (bf16_t)f; return cv.u;
}
// Wave-private LDS ordering fence. All LDS reads in edge_kernel are
// compiler-generated (their data deps ARE tracked), so rule-18's
// sched_barrier is not needed — memory clobber alone pins the ds op order,
// lgkmcnt(0) makes cross-lane writes visible. Register-only ops may still
// schedule across (wanted: overlap).
#define LDS_FENCE() asm volatile("s_waitcnt lgkmcnt(0)" ::: "memory")

// 16-level predicated sorted insertion on packed u32 keys
// key = (float_bits(d) & 0xFFFFFF00) | idx  -> total order, low idx wins ties
#define INSERTK(k_)                                                   \
    do {                                                              \
        _Pragma("unroll")                                             \
        for (int ii = KNN - 1; ii >= 1; --ii) {                       \
            const bool wr = (k_) < bk[ii];                            \
            const bool sh = (k_) < bk[ii - 1];                        \
            const unsigned nv = sh ? bk[ii - 1] : (k_);               \
            if (wr) bk[ii] = nv;                                      \
        }                                                             \
        if ((k_) < bk[0]) bk[0] = (k_);                               \
    } while (0)

// ---------------------------------------------------------------------------
// kNN (R6 2-way version — best measured): packed u32 keys, 2-way split.
// ---------------------------------------------------------------------------
__global__ __launch_bounds__(256) void knn_kernel(const float* __restrict__ points,
                                                  int* __restrict__ idx_out) {
    const int bb = blockIdx.x >> 1;
    const int qbase = (blockIdx.x & 1) * 128;
    const int t = threadIdx.x;
    const int qt = t & 127;
    const int half = t >> 7;
    const int p = qbase + qt;            // my query (within batch)

    __shared__ __align__(16) float4 sp[NP];
    __shared__ unsigned sk[128][17];

    const float* pb = points + (size_t)bb * NP * 3;
    sp[t] = make_float4(pb[t * 3 + 0], pb[t * 3 + 1], pb[t * 3 + 2], 0.f);
    __syncthreads();

    const float4 qp = sp[p];
    unsigned bk[KNN];
#pragma unroll
    for (int i = 0; i < KNN; ++i) bk[i] = 0xFFFFFFFFu;

    const int cbase = half * 128;        // wave-uniform
#pragma unroll 4
    for (int c = 0; c < 128; ++c) {
        const int cand = cbase + c;
        const float4 P = sp[cand];       // wave-uniform addr -> LDS broadcast
        const float dx = qp.x - P.x, dy = qp.y - P.y, dz = qp.z - P.z;
        const float d = fmaf(dx, dx, fmaf(dy, dy, dz * dz));
        unsigned key = (__float_as_uint(d) & 0xFFFFFF00u) | (unsigned)cand;
        key = (cand == p) ? 0xFFFFFFFFu : key;   // self-exclusion, branchless
        INSERTK(key);
    }

    if (half == 1) {
#pragma unroll
        for (int i = 0; i < KNN; ++i) sk[qt][i] = bk[i];
    }
    __syncthreads();
    if (half == 0) {
        for (int j = 0; j < KNN; ++j) {
            const unsigned key = sk[qt][j];
            if (key >= bk[KNN - 1]) break;   // ascending -> rest can't qualify
            INSERTK(key);
        }
        int* op = idx_out + ((size_t)bb * NP + p) * KNN;
#pragma unroll
        for (int i = 0; i < KNN; ++i) op[i] = (int)(bk[i] & 0xFFu);
    }
}

// ---------------------------------------------------------------------------
// fcvt: features f32 -> bf16 once (kills per-use cvt/pack VALU in edge).
// 2M elems; 262144 threads x 8 elems.
// ---------------------------------------------------------------------------
__global__ __launch_bounds__(256) void fcvt_kernel(const float* __restrict__ f,
                                                   unsigned short* __restrict__ o) {
    const int tid = blockIdx.x * 256 + threadIdx.x;
    const float4 a = ((const float4*)f)[tid * 2];
    const float4 b = ((const float4*)f)[tid * 2 + 1];
    union { unsigned short s[8]; uint4 v; } r;
    r.s[0] = f2bfu(a.x); r.s[1] = f2bfu(a.y); r.s[2] = f2bfu(a.z); r.s[3] = f2bfu(a.w);
    r.s[4] = f2bfu(b.x); r.s[5] = f2bfu(b.y); r.s[6] = f2bfu(b.z); r.s[7] = f2bfu(b.w);
    ((uint4*)o)[tid] = r.v;
}

// ---------------------------------------------------------------------------
// Prep: weights in MFMA B-fragment order (bf16) + folded BN params.
// B-frag (16x16x32): lane l holds B[ks*32 + (l>>4)*8 + j][t*16 + (l&15)].
// wsf regions (u16 offsets), 8 frags each:
//   V    [0,4096)      = w0[0:64]-w0[64:128]   (center weights, algebraic L1)
//   w0hi [4096,8192)   = w0[64:128]            (neighbor weights)
//   w1   [8192,12288)  w2 [12288,16384)  ws [16384,20480)
// bnp: scl[192], shf[192], sscl[64], sshf[64].
// ---------------------------------------------------------------------------
__global__ __launch_bounds__(256) void prep_kernel(
    const float* __restrict__ w0, const float* __restrict__ w1,
    const float* __restrict__ w2, const float* __restrict__ sc_w,
    const float* __restrict__ gammas, const float* __restrict__ betas,
    const float* __restrict__ means, const float* __restrict__ variances,
    const float* __restrict__ sc_gamma, const float* __restrict__ sc_beta,
    const float* __restrict__ sc_mean, const float* __restrict__ sc_var,
    unsigned short* __restrict__ wsf, float* __restrict__ bnp)
{
    const int tid = blockIdx.x * 256 + threadIdx.x;
    if (tid < 20480) {
        const int region = tid >> 12;          // 0:V 1:w0hi 2:w1 3:w2 4:ws
        const int e2 = tid & 4095;
        const int f = e2 >> 9;                 // frag 0..7
        const int r = e2 & 511;
        const int lane = r >> 3, j = r & 7;
        const int ks = f >> 2, t = f & 3;
        const int row = ks * 32 + (lane >> 4) * 8 + j;
        const int col = t * 16 + (lane & 15);
        float v;
        if (region == 0)      v = w0[row * 64 + col] - w0[(64 + row) * 64 + col];
        else if (region == 1) v = w0[(64 + row) * 64 + col];
        else if (region == 2) v = w1[row * 64 + col];
        else if (region == 3) v = w2[row * 64 + col];
        else                  v = sc_w[row * 64 + col];
        wsf[tid] = f2bfu(v);
    } else {
        const int e = tid - 20480;
        if (e < 192) {
            float s = gammas[e] * rsqrtf(variances[e] + EPSV);
            bnp[e] = s;
            bnp[192 + e] = betas[e] - means[e] * s;
        } else if (e < 256) {
            const int d = e - 192;
            float s = sc_gamma[d] * rsqrtf(sc_var[d] + EPSV);
            bnp[384 + d] = s;
            bnp[448 + d] = sc_beta[d] - sc_mean[d] * s;
        }
    }
}

// ---------------------------------------------------------------------------
// Edge MLP v4. One wave/block, 8 points. Algebraic L1: per-wave s0=ctr@V via
// MFMA (parked in LDS), per-point L1 = nbr@w0hi + s0 -> 8 MFMA, no center
// loads, no subtraction, no f32->bf16 packing (features pre-bf16).
// Main-loop weights: 24 frags = 96 VGPR. launch_bounds(64,3): cap 170 regs
// -> 3 waves/SIMD (R7 was reg-capped at 2).
// ---------------------------------------------------------------------------
__global__ __launch_bounds__(64, 3) void edge_kernel(
    const unsigned short* __restrict__ fbf, const int* __restrict__ knn_idx,
    const unsigned short* __restrict__ wsf, const float* __restrict__ bnp,
    float* __restrict__ out)
{
    __shared__ __align__(16) unsigned short slabA[16 * 72];  // row stride 144 B
    __shared__ __align__(16) unsigned short slabB[16 * 72];
    __shared__ float s0buf[8][64];    // per-point center term (k-invariant)
    __shared__ float ftsbuf[8][64];   // [point q][channel]

    const int l = threadIdx.x;
    const int i = l & 15;
    const int h = l >> 4;
    // bijective XCD swizzle: 4096 blocks = 8 XCDs x 512 contiguous work items
    const int wg = (blockIdx.x & 7) * 512 + (blockIdx.x >> 3);
    const int p0 = wg * 8;
    const int b = p0 >> 8;

    const bf16x8* __restrict__ WV = (const bf16x8*)(wsf);
    const bf16x8* __restrict__ W0H = (const bf16x8*)(wsf + 4096);
    const bf16x8* __restrict__ W1 = (const bf16x8*)(wsf + 8192);
    const bf16x8* __restrict__ W2 = (const bf16x8*)(wsf + 12288);

    // main-loop weights resident in registers (24 frags)
    bf16x8 w0h[2][4], w1r[2][4], w2r[2][4];
#pragma unroll
    for (int ks = 0; ks < 2; ++ks)
#pragma unroll
        for (int t = 0; t < 4; ++t) {
            w0h[ks][t] = W0H[(ks * 4 + t) * 64 + l];
            w1r[ks][t] = W1[(ks * 4 + t) * 64 + l];
            w2r[ks][t] = W2[(ks * 4 + t) * 64 + l];
        }

    float scl[3][4], shf[3][4];
#pragma unroll
    for (int L = 0; L < 3; ++L)
#pragma unroll
        for (int t = 0; t < 4; ++t) {
            scl[L][t] = bnp[L * 64 + t * 16 + i];
            shf[L][t] = bnp[192 + L * 64 + t * 16 + i];
        }

    // ---- prologue: s0 = ctr @ V for this wave's 8 points (rows 8..15 dup) ----
    {
        const unsigned short* cp = fbf + (size_t)(p0 + (i & 7)) * NC;
        bf16x8 a0 = *(const bf16x8*)(cp + 8 * h);        // k = 0..31 slice
        bf16x8 a1 = *(const bf16x8*)(cp + 32 + 8 * h);   // k = 32..63 slice
#pragma unroll
        for (int t = 0; t < 4; ++t) {
            f32x4 acc = {0.f, 0.f, 0.f, 0.f};
            acc = mfma16(a0, WV[t * 64 + l], acc);
            acc = mfma16(a1, WV[(4 + t) * 64 + l], acc);
            if (h < 2) {
#pragma unroll
                for (int r = 0; r < 4; ++r)
                    s0buf[h * 4 + r][t * 16 + i] = acc[r];
            }
        }
    }
    // preload all 8 neighbor indices (lane's k = i); loop fully unrolled
    int nks[8];
#pragma unroll
    for (int q = 0; q < 8; ++q) nks[q] = knn_idx[(size_t)(p0 + q) * KNN + i];
    LDS_FENCE();

    // prime point 0's neighbor A-fragments
    bf16x8 fc0, fc1;
    {
        const unsigned short* sp = fbf + (size_t)(b * NP + nks[0]) * NC;
        fc0 = *(const bf16x8*)(sp + 8 * h);
        fc1 = *(const bf16x8*)(sp + 32 + 8 * h);
    }

#pragma unroll
    for (int q = 0; q < 8; ++q) {
        // ---- layer 1: nbr @ w0hi + s0 -> slabA ----
        float s0q[4];
#pragma unroll
        for (int t = 0; t < 4; ++t) s0q[t] = s0buf[q][t * 16 + i];
#pragma unroll
        for (int t = 0; t < 4; ++t) {
            f32x4 acc = {0.f, 0.f, 0.f, 0.f};
            acc = mfma16(fc0, w0h[0][t], acc);
            acc = mfma16(fc1, w0h[1][t], acc);
#pragma unroll
            for (int r = 0; r < 4; ++r) {
                float y = fmaxf(fmaf(acc[r] + s0q[t], scl[0][t], shf[0][t]), 0.f);
                slabA[(h * 4 + r) * 72 + t * 16 + i] = f2bfu(y);
            }
        }
        // prefetch next point's fragments (issued before fences -> latency
        // overlaps L2+L3 of this point)
        bf16x8 fn0, fn1;
        if (q < 7) {
            const unsigned short* sp = fbf + (size_t)(b * NP + nks[(q + 1) & 7]) * NC;
            fn0 = *(const bf16x8*)(sp + 8 * h);
            fn1 = *(const bf16x8*)(sp + 32 + 8 * h);
        }
        LDS_FENCE();

        // ---- layer 2 -> slabB ----
        {
            bf16x8 x0 = *(const bf16x8*)(slabA + i * 72 + h * 8);
            bf16x8 x1 = *(const bf16x8*)(slabA + i * 72 + h * 8 + 32);
#pragma unroll
            for (int t = 0; t < 4; ++t) {
                f32x4 acc = {0.f, 0.f, 0.f, 0.f};
                acc = mfma16(x0, w1r[0][t], acc);
                acc = mfma16(x1, w1r[1][t], acc);
#pragma unroll
                for (int r = 0; r < 4; ++r) {
                    float y = fmaxf(fmaf(acc[r], scl[1][t], shf[1][t]), 0.f);
                    slabB[(h * 4 + r) * 72 + t * 16 + i] = f2bfu(y);
                }
            }
        }
        LDS_FENCE();

        // ---- layer 3 + mean over k -> ftsbuf ----
        {
            bf16x8 x0 = *(const bf16x8*)(slabB + i * 72 + h * 8);
            bf16x8 x1 = *(const bf16x8*)(slabB + i * 72 + h * 8 + 32);
#pragma unroll
            for (int t = 0; t < 4; ++t) {
                f32x4 acc = {0.f, 0.f, 0.f, 0.f};
                acc = mfma16(x0, w2r[0][t], acc);
                acc = mfma16(x1, w2r[1][t], acc);
                float s = 0.f;
#pragma unroll
                for (int r = 0; r < 4; ++r)
                    s += fmaxf(fmaf(acc[r], scl[2][t], shf[2][t]), 0.f);
                s += __shfl_xor(s, 16, 64);  // reduce over h-groups (same i)
                s += __shfl_xor(s, 32, 64);
                if (h == 0) ftsbuf[q][t * 16 + i] = s * (1.f / 16.f);
            }
        }
        LDS_FENCE();  // slab WAR for next iter + ftsbuf visibility
        fc0 = fn0; fc1 = fn1;
    }

    // ---- shortcut GEMM + epilogue: rows 0..7 = this wave's 8 points ----
    {
        const bf16x8* __restrict__ WS = (const bf16x8*)(wsf + 16384);
        float sscl[4], sshf[4];
#pragma unroll
        for (int t = 0; t < 4; ++t) {
            sscl[t] = bnp[384 + t * 16 + i];
            sshf[t] = bnp[448 + t * 16 + i];
        }
        const unsigned short* fp = fbf + (size_t)(p0 + (i & 7)) * NC;  // rows 8..15 dup
        bf16x8 a0 = *(const bf16x8*)(fp + 8 * h);
        bf16x8 a1 = *(const bf16x8*)(fp + 32 + 8 * h);
#pragma unroll
        for (int t = 0; t < 4; ++t) {
            f32x4 acc = {0.f, 0.f, 0.f, 0.f};
            acc = mfma16(a0, WS[t * 64 + l], acc);
            acc = mfma16(a1, WS[(4 + t) * 64 + l], acc);
            if (h < 2) {   // C rows 0..7 = real points; 8..15 are duplicates
#pragma unroll
                for (int r = 0; r < 4; ++r) {
                    const int q = h * 4 + r;
                    out[(size_t)(p0 + q) * NC + t * 16 + i] =
                        fmaxf(fmaf(acc[r], sscl[t], sshf[t]) + ftsbuf[q][t * 16 + i], 0.f);
                }
            }
        }
    }
}

extern "C" void kernel_launch(void* const* d_in, const int* in_sizes, int n_in,
                              void* d_out, int out_size, void* d_ws, size_t ws_size,
                              hipStream_t stream) {
    const float* points    = (const float*)d_in[0];
    const float* features  = (const float*)d_in[1];
    const float* w0        = (const float*)d_in[2];
    const float* w1        = (const float*)d_in[3];
    const float* w2        = (const float*)d_in[4];
    const float* gammas    = (const float*)d_in[5];
    const float* betas     = (const float*)d_in[6];
    const float* means     = (const float*)d_in[7];
    const float* variances = (const float*)d_in[8];
    const float* sc_w      = (const float*)d_in[9];
    const float* sc_gamma  = (const float*)d_in[10];
    const float* sc_beta   = (const float*)d_in[11];
    const float* sc_mean   = (const float*)d_in[12];
    const float* sc_var    = (const float*)d_in[13];
    float* out = (float*)d_out;

    int* knn_buf = (int*)d_ws;                                          // 2 MB
    unsigned short* fbf = (unsigned short*)((char*)d_ws + (1 << 21));   // 4 MB
    unsigned short* wsf = (unsigned short*)((char*)d_ws + (3 << 21));   // 40 KB
    float* bnp = (float*)((char*)d_ws + (3 << 21) + 40960);             // 2 KB

    prep_kernel<<<81, 256, 0, stream>>>(w0, w1, w2, sc_w, gammas, betas, means,
                                        variances, sc_gamma, sc_beta, sc_mean,
                                        sc_var, wsf, bnp);
    fcvt_kernel<<<1024, 256, 0, stream>>>(features, fbf);
    knn_kernel<<<NBATCH * 2, 256, 0, stream>>>(points, knn_buf);
    edge_kernel<<<NBATCH * NP / 8, 64, 0, stream>>>(fbf, knn_buf, wsf, bnp, out);
}

// Round 9
// 67.514 us; speedup vs baseline: 1.0560x; 1.0040x over previous
//
#include <hip/hip_runtime.h>
#include <math.h>

#define NBATCH 128
#define NP 256
#define NC 64
#define KNN 16
#define EPSV 1e-3f

typedef __bf16 bf16_t;
typedef bf16_t bf16x8 __attribute__((ext_vector_type(8)));
typedef float f32x4 __attribute__((ext_vector_type(4)));

static __device__ __forceinline__ f32x4 mfma16(bf16x8 a, bf16x8 b, f32x4 c) {
    return __builtin_amdgcn_mfma_f32_16x16x32_bf16(a, b, c, 0, 0, 0);
}
static __device__ __forceinline__ unsigned short f2bfu(float f) {
    union { bf16_t b; unsigned short u; } cv; cv.b = (bf16_t)f; return cv.u;
}
// Wave-private LDS ordering fence: lgkmcnt is a per-wave HW counter, so this
// only waits on THIS wave's outstanding LDS ops. memory clobber pins ds-op
// program order; register-only ops may still schedule across (wanted).
#define LDS_FENCE() asm volatile("s_waitcnt lgkmcnt(0)" ::: "memory")

// 16-level predicated sorted insertion on packed u32 keys
// key = (float_bits(d) & 0xFFFFFF00) | idx  -> total order, low idx wins ties
#define INSERTK(k_)                                                   \
    do {                                                              \
        _Pragma("unroll")                                             \
        for (int ii = KNN - 1; ii >= 1; --ii) {                       \
            const bool wr = (k_) < bk[ii];                            \
            const bool sh = (k_) < bk[ii - 1];                        \
            const unsigned nv = sh ? bk[ii - 1] : (k_);               \
            if (wr) bk[ii] = nv;                                      \
        }                                                             \
        if ((k_) < bk[0]) bk[0] = (k_);                               \
    } while (0)

// ---------------------------------------------------------------------------
// kNN (R6 2-way version — best measured): packed u32 keys, 2-way split.
// ---------------------------------------------------------------------------
__global__ __launch_bounds__(256) void knn_kernel(const float* __restrict__ points,
                                                  int* __restrict__ idx_out) {
    const int bb = blockIdx.x >> 1;
    const int qbase = (blockIdx.x & 1) * 128;
    const int t = threadIdx.x;
    const int qt = t & 127;
    const int half = t >> 7;
    const int p = qbase + qt;            // my query (within batch)

    __shared__ __align__(16) float4 sp[NP];
    __shared__ unsigned sk[128][17];

    const float* pb = points + (size_t)bb * NP * 3;
    sp[t] = make_float4(pb[t * 3 + 0], pb[t * 3 + 1], pb[t * 3 + 2], 0.f);
    __syncthreads();

    const float4 qp = sp[p];
    unsigned bk[KNN];
#pragma unroll
    for (int i = 0; i < KNN; ++i) bk[i] = 0xFFFFFFFFu;

    const int cbase = half * 128;        // wave-uniform
#pragma unroll 4
    for (int c = 0; c < 128; ++c) {
        const int cand = cbase + c;
        const float4 P = sp[cand];       // wave-uniform addr -> LDS broadcast
        const float dx = qp.x - P.x, dy = qp.y - P.y, dz = qp.z - P.z;
        const float d = fmaf(dx, dx, fmaf(dy, dy, dz * dz));
        unsigned key = (__float_as_uint(d) & 0xFFFFFF00u) | (unsigned)cand;
        key = (cand == p) ? 0xFFFFFFFFu : key;   // self-exclusion, branchless
        INSERTK(key);
    }

    if (half == 1) {
#pragma unroll
        for (int i = 0; i < KNN; ++i) sk[qt][i] = bk[i];
    }
    __syncthreads();
    if (half == 0) {
        for (int j = 0; j < KNN; ++j) {
            const unsigned key = sk[qt][j];
            if (key >= bk[KNN - 1]) break;   // ascending -> rest can't qualify
            INSERTK(key);
        }
        int* op = idx_out + ((size_t)bb * NP + p) * KNN;
#pragma unroll
        for (int i = 0; i < KNN; ++i) op[i] = (int)(bk[i] & 0xFFu);
    }
}

// ---------------------------------------------------------------------------
// fcvt: features f32 -> bf16 once (kills per-use cvt/pack VALU in edge).
// ---------------------------------------------------------------------------
__global__ __launch_bounds__(256) void fcvt_kernel(const float* __restrict__ f,
                                                   unsigned short* __restrict__ o) {
    const int tid = blockIdx.x * 256 + threadIdx.x;
    const float4 a = ((const float4*)f)[tid * 2];
    const float4 b = ((const float4*)f)[tid * 2 + 1];
    union { unsigned short s[8]; uint4 v; } r;
    r.s[0] = f2bfu(a.x); r.s[1] = f2bfu(a.y); r.s[2] = f2bfu(a.z); r.s[3] = f2bfu(a.w);
    r.s[4] = f2bfu(b.x); r.s[5] = f2bfu(b.y); r.s[6] = f2bfu(b.z); r.s[7] = f2bfu(b.w);
    ((uint4*)o)[tid] = r.v;
}

// ---------------------------------------------------------------------------
// Prep: weights in MFMA B-fragment order (bf16) + folded BN params.
// B-frag (16x16x32): lane l holds B[ks*32 + (l>>4)*8 + j][t*16 + (l&15)].
// wsf regions (u16 offsets), 8 frags each:
//   V    [0,4096)      = w0[0:64]-w0[64:128]   (center weights, algebraic L1)
//   w0hi [4096,8192)   = w0[64:128]            (neighbor weights)
//   w1   [8192,12288)  w2 [12288,16384)  ws [16384,20480)
// bnp: scl[192], shf[192], sscl[64], sshf[64].
// ---------------------------------------------------------------------------
__global__ __launch_bounds__(256) void prep_kernel(
    const float* __restrict__ w0, const float* __restrict__ w1,
    const float* __restrict__ w2, const float* __restrict__ sc_w,
    const float* __restrict__ gammas, const float* __restrict__ betas,
    const float* __restrict__ means, const float* __restrict__ variances,
    const float* __restrict__ sc_gamma, const float* __restrict__ sc_beta,
    const float* __restrict__ sc_mean, const float* __restrict__ sc_var,
    unsigned short* __restrict__ wsf, float* __restrict__ bnp)
{
    const int tid = blockIdx.x * 256 + threadIdx.x;
    if (tid < 20480) {
        const int region = tid >> 12;          // 0:V 1:w0hi 2:w1 3:w2 4:ws
        const int e2 = tid & 4095;
        const int f = e2 >> 9;                 // frag 0..7
        const int r = e2 & 511;
        const int lane = r >> 3, j = r & 7;
        const int ks = f >> 2, t = f & 3;
        const int row = ks * 32 + (lane >> 4) * 8 + j;
        const int col = t * 16 + (lane & 15);
        float v;
        if (region == 0)      v = w0[row * 64 + col] - w0[(64 + row) * 64 + col];
        else if (region == 1) v = w0[(64 + row) * 64 + col];
        else if (region == 2) v = w1[row * 64 + col];
        else if (region == 3) v = w2[row * 64 + col];
        else                  v = sc_w[row * 64 + col];
        wsf[tid] = f2bfu(v);
    } else {
        const int e = tid - 20480;
        if (e < 192) {
            float s = gammas[e] * rsqrtf(variances[e] + EPSV);
            bnp[e] = s;
            bnp[192 + e] = betas[e] - means[e] * s;
        } else if (e < 256) {
            const int d = e - 192;
            float s = sc_gamma[d] * rsqrtf(sc_var[d] + EPSV);
            bnp[384 + d] = s;
            bnp[448 + d] = sc_beta[d] - sc_mean[d] * s;
        }
    }
}

// ---------------------------------------------------------------------------
// Edge MLP v5: 4 INDEPENDENT waves per workgroup (256 thr), each wave owns 8
// points and a private LDS region — zero __syncthreads, per-wave lgkmcnt
// fences. Rationale: R4-R8 showed single-wave WGs pin occupancy at ~6 waves/CU
// regardless of VGPR/LDS headroom (WG dispatch/slot limit); packing 4 waves
// per WG targets 16 waves/CU (LDS-capped at 4 blocks x 34.8 KB).
// Per-wave program unchanged from R8 (algebraic L1, pre-bf16 features).
// ---------------------------------------------------------------------------
__global__ __launch_bounds__(256) void edge_kernel(
    const unsigned short* __restrict__ fbf, const int* __restrict__ knn_idx,
    const unsigned short* __restrict__ wsf, const float* __restrict__ bnp,
    float* __restrict__ out)
{
    __shared__ __align__(16) unsigned short slabA[4][16 * 72];
    __shared__ __align__(16) unsigned short slabB[4][16 * 72];
    __shared__ float s0buf[4][8][64];    // per-point center term (k-invariant)
    __shared__ float ftsbuf[4][8][64];   // [point q][channel]

    const int tid = threadIdx.x;
    const int wid = tid >> 6;
    const int l = tid & 63;
    const int i = l & 15;
    const int h = l >> 4;
    // bijective XCD swizzle: 1024 blocks = 8 XCDs x 128 contiguous work items
    const int wg = (blockIdx.x & 7) * 128 + (blockIdx.x >> 3);
    const int p0 = (wg * 4 + wid) * 8;
    const int b = p0 >> 8;

    unsigned short* sA = slabA[wid];
    unsigned short* sB = slabB[wid];

    const bf16x8* __restrict__ WV = (const bf16x8*)(wsf);
    const bf16x8* __restrict__ W0H = (const bf16x8*)(wsf + 4096);
    const bf16x8* __restrict__ W1 = (const bf16x8*)(wsf + 8192);
    const bf16x8* __restrict__ W2 = (const bf16x8*)(wsf + 12288);

    // main-loop weights resident in registers (24 frags = 96 VGPR)
    bf16x8 w0h[2][4], w1r[2][4], w2r[2][4];
#pragma unroll
    for (int ks = 0; ks < 2; ++ks)
#pragma unroll
        for (int t = 0; t < 4; ++t) {
            w0h[ks][t] = W0H[(ks * 4 + t) * 64 + l];
            w1r[ks][t] = W1[(ks * 4 + t) * 64 + l];
            w2r[ks][t] = W2[(ks * 4 + t) * 64 + l];
        }

    float scl[3][4], shf[3][4];
#pragma unroll
    for (int L = 0; L < 3; ++L)
#pragma unroll
        for (int t = 0; t < 4; ++t) {
            scl[L][t] = bnp[L * 64 + t * 16 + i];
            shf[L][t] = bnp[192 + L * 64 + t * 16 + i];
        }

    // ---- prologue: s0 = ctr @ V for this wave's 8 points (rows 8..15 dup) ----
    {
        const unsigned short* cp = fbf + (size_t)(p0 + (i & 7)) * NC;
        bf16x8 a0 = *(const bf16x8*)(cp + 8 * h);        // k = 0..31 slice
        bf16x8 a1 = *(const bf16x8*)(cp + 32 + 8 * h);   // k = 32..63 slice
#pragma unroll
        for (int t = 0; t < 4; ++t) {
            f32x4 acc = {0.f, 0.f, 0.f, 0.f};
            acc = mfma16(a0, WV[t * 64 + l], acc);
            acc = mfma16(a1, WV[(4 + t) * 64 + l], acc);
            if (h < 2) {
#pragma unroll
                for (int r = 0; r < 4; ++r)
                    s0buf[wid][h * 4 + r][t * 16 + i] = acc[r];
            }
        }
    }
    // preload all 8 neighbor indices (lane's k = i)
    int nks[8];
#pragma unroll
    for (int q = 0; q < 8; ++q) nks[q] = knn_idx[(size_t)(p0 + q) * KNN + i];
    LDS_FENCE();

    // prime point 0's neighbor A-fragments
    bf16x8 fc0, fc1;
    {
        const unsigned short* sp = fbf + (size_t)(b * NP + nks[0]) * NC;
        fc0 = *(const bf16x8*)(sp + 8 * h);
        fc1 = *(const bf16x8*)(sp + 32 + 8 * h);
    }

#pragma unroll
    for (int q = 0; q < 8; ++q) {
        // ---- layer 1: nbr @ w0hi + s0 -> sA ----
        float s0q[4];
#pragma unroll
        for (int t = 0; t < 4; ++t) s0q[t] = s0buf[wid][q][t * 16 + i];
#pragma unroll
        for (int t = 0; t < 4; ++t) {
            f32x4 acc = {0.f, 0.f, 0.f, 0.f};
            acc = mfma16(fc0, w0h[0][t], acc);
            acc = mfma16(fc1, w0h[1][t], acc);
#pragma unroll
            for (int r = 0; r < 4; ++r) {
                float y = fmaxf(fmaf(acc[r] + s0q[t], scl[0][t], shf[0][t]), 0.f);
                sA[(h * 4 + r) * 72 + t * 16 + i] = f2bfu(y);
            }
        }
        // prefetch next point's fragments (latency overlaps this point's tail)
        bf16x8 fn0, fn1;
        if (q < 7) {
            const unsigned short* sp = fbf + (size_t)(b * NP + nks[(q + 1) & 7]) * NC;
            fn0 = *(const bf16x8*)(sp + 8 * h);
            fn1 = *(const bf16x8*)(sp + 32 + 8 * h);
        }
        LDS_FENCE();

        // ---- layer 2 -> sB ----
        {
            bf16x8 x0 = *(const bf16x8*)(sA + i * 72 + h * 8);
            bf16x8 x1 = *(const bf16x8*)(sA + i * 72 + h * 8 + 32);
#pragma unroll
            for (int t = 0; t < 4; ++t) {
                f32x4 acc = {0.f, 0.f, 0.f, 0.f};
                acc = mfma16(x0, w1r[0][t], acc);
                acc = mfma16(x1, w1r[1][t], acc);
#pragma unroll
                for (int r = 0; r < 4; ++r) {
                    float y = fmaxf(fmaf(acc[r], scl[1][t], shf[1][t]), 0.f);
                    sB[(h * 4 + r) * 72 + t * 16 + i] = f2bfu(y);
                }
            }
        }
        LDS_FENCE();

        // ---- layer 3 + mean over k -> ftsbuf ----
        {
            bf16x8 x0 = *(const bf16x8*)(sB + i * 72 + h * 8);
            bf16x8 x1 = *(const bf16x8*)(sB + i * 72 + h * 8 + 32);
#pragma unroll
            for (int t = 0; t < 4; ++t) {
                f32x4 acc = {0.f, 0.f, 0.f, 0.f};
                acc = mfma16(x0, w2r[0][t], acc);
                acc = mfma16(x1, w2r[1][t], acc);
                float s = 0.f;
#pragma unroll
                for (int r = 0; r < 4; ++r)
                    s += fmaxf(fmaf(acc[r], scl[2][t], shf[2][t]), 0.f);
                s += __shfl_xor(s, 16, 64);  // reduce over h-groups (same i)
                s += __shfl_xor(s, 32, 64);
                if (h == 0) ftsbuf[wid][q][t * 16 + i] = s * (1.f / 16.f);
            }
        }
        LDS_FENCE();  // slab WAR for next iter + ftsbuf visibility
        fc0 = fn0; fc1 = fn1;
    }

    // ---- shortcut GEMM + epilogue: rows 0..7 = this wave's 8 points ----
    {
        const bf16x8* __restrict__ WS = (const bf16x8*)(wsf + 16384);
        float sscl[4], sshf[4];
#pragma unroll
        for (int t = 0; t < 4; ++t) {
            sscl[t] = bnp[384 + t * 16 + i];
            sshf[t] = bnp[448 + t * 16 + i];
        }
        const unsigned short* fp = fbf + (size_t)(p0 + (i & 7)) * NC;  // rows 8..15 dup
        bf16x8 a0 = *(const bf16x8*)(fp + 8 * h);
        bf16x8 a1 = *(const bf16x8*)(fp + 32 + 8 * h);
#pragma unroll
        for (int t = 0; t < 4; ++t) {
            f32x4 acc = {0.f, 0.f, 0.f, 0.f};
            acc = mfma16(a0, WS[t * 64 + l], acc);
            acc = mfma16(a1, WS[(4 + t) * 64 + l], acc);
            if (h < 2) {   // C rows 0..7 = real points; 8..15 are duplicates
#pragma unroll
                for (int r = 0; r < 4; ++r) {
                    const int q = h * 4 + r;
                    out[(size_t)(p0 + q) * NC + t * 16 + i] =
                        fmaxf(fmaf(acc[r], sscl[t], sshf[t]) + ftsbuf[wid][q][t * 16 + i], 0.f);
                }
            }
        }
    }
}

extern "C" void kernel_launch(void* const* d_in, const int* in_sizes, int n_in,
                              void* d_out, int out_size, void* d_ws, size_t ws_size,
                              hipStream_t stream) {
    const float* points    = (const float*)d_in[0];
    const float* features  = (const float*)d_in[1];
    const float* w0        = (const float*)d_in[2];
    const float* w1        = (const float*)d_in[3];
    const float* w2        = (const float*)d_in[4];
    const float* gammas    = (const float*)d_in[5];
    const float* betas     = (const float*)d_in[6];
    const float* means     = (const float*)d_in[7];
    const float* variances = (const float*)d_in[8];
    const float* sc_w      = (const float*)d_in[9];
    const float* sc_gamma  = (const float*)d_in[10];
    const float* sc_beta   = (const float*)d_in[11];
    const float* sc_mean   = (const float*)d_in[12];
    const float* sc_var    = (const float*)d_in[13];
    float* out = (float*)d_out;

    int* knn_buf = (int*)d_ws;                                          // 2 MB
    unsigned short* fbf = (unsigned short*)((char*)d_ws + (1 << 21));   // 4 MB
    unsigned short* wsf = (unsigned short*)((char*)d_ws + (3 << 21));   // 40 KB
    float* bnp = (float*)((char*)d_ws + (3 << 21) + 40960);             // 2 KB

    prep_kernel<<<81, 256, 0, stream>>>(w0, w1, w2, sc_w, gammas, betas, means,
                                        variances, sc_gamma, sc_beta, sc_mean,
                                        sc_var, wsf, bnp);
    fcvt_kernel<<<1024, 256, 0, stream>>>(features, fbf);
    knn_kernel<<<NBATCH * 2, 256, 0, stream>>>(points, knn_buf);
    edge_kernel<<<NBATCH * NP / 32, 256, 0, stream>>>(fbf, knn_buf, wsf, bnp, out);
}